// Round 5
// baseline (74.453 us; speedup 1.0000x reference)
//
#include <hip/hip_runtime.h>
#include <hip/hip_bf16.h>

#define NTOK 32768
#define NE   1024
#define DD   256
#define BM   32

typedef __attribute__((ext_vector_type(4))) float  f32x4;
typedef __attribute__((ext_vector_type(8))) short  bf16x8;

// ---- prep1: en10[row] = -10 * ||emb_row||^2 ----
__global__ __launch_bounds__(256) void prep_norm_kernel(
    const float* __restrict__ emb, float* __restrict__ en10)
{
    const int t = threadIdx.x;
    const int row = blockIdx.x * 4 + (t >> 6);   // one wave per row
    const int q = t & 63;
    f32x4 v = *(const f32x4*)(emb + (size_t)row * DD + q * 4);
    float ss = v.x * v.x + v.y * v.y + v.z * v.z + v.w * v.w;
#pragma unroll
    for (int off = 32; off; off >>= 1) ss += __shfl_xor(ss, off, 64);
    if (q == 0) en10[row] = -10.f * ss;
}

// ---- prep2: pack bf16(-2*emb) in MFMA B-fragment-linear order ----
// slot ((j2*8+kk)*64 + l) holds the 16B lane l=(lr,lg) consumes for
// col-block j2 (16 cols), k-chunk kk: emb[j2*16+lr][kk*32+lg*8 .. +8] * (-2)
__global__ __launch_bounds__(512) void prep_pack_kernel(
    const float* __restrict__ emb, __hip_bfloat16* __restrict__ embp)
{
    const int j2 = blockIdx.x;        // 0..63
    const int kk = threadIdx.x >> 6;  // 0..7
    const int l  = threadIdx.x & 63;
    const int lr = l & 15, lg = l >> 4;
    const float* src = emb + (size_t)(j2 * 16 + lr) * DD + kk * 32 + lg * 8;
    f32x4 a = *(const f32x4*)src;
    f32x4 b = *(const f32x4*)(src + 4);
    alignas(16) __hip_bfloat16 h[8];
    h[0] = __float2bfloat16(-2.f * a.x); h[1] = __float2bfloat16(-2.f * a.y);
    h[2] = __float2bfloat16(-2.f * a.z); h[3] = __float2bfloat16(-2.f * a.w);
    h[4] = __float2bfloat16(-2.f * b.x); h[5] = __float2bfloat16(-2.f * b.y);
    h[6] = __float2bfloat16(-2.f * b.z); h[7] = __float2bfloat16(-2.f * b.w);
    *(bf16x8*)(embp + ((size_t)(j2 * 8 + kk) * 64 + l) * 8) = *(const bf16x8*)h;
}

// ---- main: fused dist-GEMM + double-exp + row softmax ----
// block = 1024 threads (16 waves); tile = 32 rows x 1024 cols;
// wave w owns cols [w*64, w*64+64) x all 32 rows (acc[2][4]).
// A staged in LDS in fragment-linear planes af[rg*8+kk][slot l][8] (pad 65).
__global__ __launch_bounds__(1024) void sq_main_kernel(
    const float* __restrict__ z, const __hip_bfloat16* __restrict__ embp,
    const float* __restrict__ en10, float* __restrict__ out)
{
    __shared__ alignas(16) __hip_bfloat16 af[16][65][8];  // 16.6 KB, pad slot kills write conflicts
    __shared__ float zn10_s[BM];
    __shared__ float red[BM][16];
    __shared__ float rowinv[BM];

    const int t  = threadIdx.x;
    const int n0 = blockIdx.x * BM;
    const int w  = t >> 6;     // wave id 0..15 (stages rows w, w+16; owns col block w)
    const int l  = t & 63;     // lane

    // ---- stage z: wave w stages rows rg*16+w; fragment-linear bf16 to LDS ----
#pragma unroll
    for (int rg = 0; rg < 2; ++rg) {
        const int r = rg * 16 + w;
        f32x4 v = *(const f32x4*)(z + (size_t)(n0 + r) * DD + l * 4);
        float ss = v.x * v.x + v.y * v.y + v.z * v.z + v.w * v.w;
#pragma unroll
        for (int off = 32; off; off >>= 1) ss += __shfl_xor(ss, off, 64);
        if (l == 0) zn10_s[r] = -10.f * ss;
        alignas(8) __hip_bfloat16 h[4];
        h[0] = __float2bfloat16(v.x); h[1] = __float2bfloat16(v.y);
        h[2] = __float2bfloat16(v.z); h[3] = __float2bfloat16(v.w);
        // cols 4l..4l+3 -> plane kk=l>>3, slot lg_d*16+lr_d, half l&1
        *(short4*)&af[rg * 8 + (l >> 3)][((l >> 1) & 3) * 16 + w][(l & 1) * 4] =
            *(const short4*)h;
    }
    __syncthreads();

    const int lr = l & 15, lg = l >> 4;   // B-col (and C col) / k-group

    // ---- GEMM: acc[rg][j]; A re-read per kk (lane-linear, conflict-free) ----
    f32x4 acc[2][4];
#pragma unroll
    for (int rg = 0; rg < 2; ++rg)
#pragma unroll
        for (int j = 0; j < 4; ++j) acc[rg][j] = (f32x4){0.f, 0.f, 0.f, 0.f};

    const __hip_bfloat16* bbase = embp + ((size_t)(w * 4) * 8 * 64 + l) * 8;
#pragma unroll
    for (int kk = 0; kk < 8; ++kk) {
        bf16x8 a0 = *(const bf16x8*)&af[kk][l][0];
        bf16x8 a1 = *(const bf16x8*)&af[8 + kk][l][0];
#pragma unroll
        for (int j = 0; j < 4; ++j) {
            bf16x8 b = *(const bf16x8*)(bbase + (size_t)(j * 8 + kk) * 64 * 8);
            acc[0][j] = __builtin_amdgcn_mfma_f32_16x16x32_bf16(a0, b, acc[0][j], 0, 0, 0);
            acc[1][j] = __builtin_amdgcn_mfma_f32_16x16x32_bf16(a1, b, acc[1][j], 0, 0, 0);
        }
    }

    // ---- epilogue: tt = -10*d ; u = 10*exp(tt) ; e = exp(u) ; u in (0,10] ----
    float zr10[2][4];
#pragma unroll
    for (int rg = 0; rg < 2; ++rg)
#pragma unroll
        for (int r = 0; r < 4; ++r) zr10[rg][r] = zn10_s[rg * 16 + lg * 4 + r];

    float sum[2][4] = {{0.f, 0.f, 0.f, 0.f}, {0.f, 0.f, 0.f, 0.f}};
#pragma unroll
    for (int j = 0; j < 4; ++j) {
        const float ec10 = en10[w * 64 + j * 16 + lr];
#pragma unroll
        for (int rg = 0; rg < 2; ++rg)
#pragma unroll
            for (int r = 0; r < 4; ++r) {
                const float tt = fmaf(-10.0f, acc[rg][j][r], zr10[rg][r] + ec10);
                const float u  = 10.0f * __expf(tt);
                const float e  = __expf(u);
                acc[rg][j][r] = e;
                sum[rg][r] += e;
            }
    }
    // sum across the 16 lanes sharing lg (butterfly within 16-lane groups)
#pragma unroll
    for (int off = 1; off < 16; off <<= 1)
#pragma unroll
        for (int rg = 0; rg < 2; ++rg)
#pragma unroll
            for (int r = 0; r < 4; ++r) sum[rg][r] += __shfl_xor(sum[rg][r], off, 64);
    if (lr == 0)
#pragma unroll
        for (int rg = 0; rg < 2; ++rg)
#pragma unroll
            for (int r = 0; r < 4; ++r) red[rg * 16 + lg * 4 + r][w] = sum[rg][r];
    __syncthreads();

    // ---- stage-2 reduce: 32 threads -> rowinv[32], then broadcast ----
    if (t < BM) {
        const float* p = red[t];
        float s = 0.f;
#pragma unroll
        for (int q = 0; q < 16; ++q) s += p[q];
        rowinv[t] = 1.0f / s;
    }
    __syncthreads();

    float inv[2][4];
#pragma unroll
    for (int rg = 0; rg < 2; ++rg)
#pragma unroll
        for (int r = 0; r < 4; ++r) inv[rg][r] = rowinv[rg * 16 + lg * 4 + r];

    // ---- store: per (j,rg,r) a wave writes 4 x 64B contiguous segments ----
#pragma unroll
    for (int j = 0; j < 4; ++j) {
        const int col = w * 64 + j * 16 + lr;
#pragma unroll
        for (int rg = 0; rg < 2; ++rg)
#pragma unroll
            for (int r = 0; r < 4; ++r) {
                const int row = rg * 16 + lg * 4 + r;
                out[(size_t)(n0 + row) * NE + col] = acc[rg][j][r] * inv[rg][r];
            }
    }
}

extern "C" void kernel_launch(void* const* d_in, const int* in_sizes, int n_in,
                              void* d_out, int out_size, void* d_ws, size_t ws_size,
                              hipStream_t stream) {
    (void)in_sizes; (void)n_in; (void)out_size; (void)ws_size;
    const float* z   = (const float*)d_in[0];
    const float* emb = (const float*)d_in[1];
    float* out = (float*)d_out;
    __hip_bfloat16* embp = (__hip_bfloat16*)d_ws;
    float* en10 = (float*)((char*)d_ws + (size_t)NE * DD * sizeof(__hip_bfloat16));

    hipLaunchKernelGGL(prep_norm_kernel, dim3(NE / 4), dim3(256), 0, stream,
                       emb, en10);
    hipLaunchKernelGGL(prep_pack_kernel, dim3(64), dim3(512), 0, stream,
                       emb, embp);
    hipLaunchKernelGGL(sq_main_kernel, dim3(NTOK / BM), dim3(1024), 0, stream,
                       z, embp, en10, out);
}

// Round 6
// 70.133 us; speedup vs baseline: 1.0616x; 1.0616x over previous
//
#include <hip/hip_runtime.h>
#include <hip/hip_bf16.h>

#define NTOK 32768
#define NE   1024
#define DD   256
#define BM   32

typedef __attribute__((ext_vector_type(4))) float  f32x4;

// ---- prep1: en10[row] = -10 * ||emb_row||^2 ----
__global__ __launch_bounds__(256) void prep_norm_kernel(
    const float* __restrict__ emb, float* __restrict__ en10)
{
    const int t = threadIdx.x;
    const int row = blockIdx.x * 4 + (t >> 6);   // one wave per row
    const int q = t & 63;
    f32x4 v = *(const f32x4*)(emb + (size_t)row * DD + q * 4);
    float ss = v.x * v.x + v.y * v.y + v.z * v.z + v.w * v.w;
#pragma unroll
    for (int off = 32; off; off >>= 1) ss += __shfl_xor(ss, off, 64);
    if (q == 0) en10[row] = -10.f * ss;
}

// ---- prep2: pack fp8(-1024*emb) in MFMA B-fragment-linear order ----
// slot ((j2*8+kk)*64 + l) holds the 8B lane l=(lr,lg) consumes for
// col-block j2 (16 cols), k-chunk kk: emb[j2*16+lr][kk*32+lg*8 .. +8] * (-1024)
__global__ __launch_bounds__(512) void prep_pack_kernel(
    const float* __restrict__ emb, unsigned char* __restrict__ embp)
{
    const int j2 = blockIdx.x;        // 0..63
    const int kk = threadIdx.x >> 6;  // 0..7
    const int l  = threadIdx.x & 63;
    const int lr = l & 15, lg = l >> 4;
    const float* src = emb + (size_t)(j2 * 16 + lr) * DD + kk * 32 + lg * 8;
    f32x4 a = *(const f32x4*)src;
    f32x4 b = *(const f32x4*)(src + 4);
    const float s = -1024.0f;
    int lo = 0, hi = 0;
    lo = __builtin_amdgcn_cvt_pk_fp8_f32(s * a.x, s * a.y, lo, false);
    lo = __builtin_amdgcn_cvt_pk_fp8_f32(s * a.z, s * a.w, lo, true);
    hi = __builtin_amdgcn_cvt_pk_fp8_f32(s * b.x, s * b.y, hi, false);
    hi = __builtin_amdgcn_cvt_pk_fp8_f32(s * b.z, s * b.w, hi, true);
    uint2 p; p.x = (unsigned)lo; p.y = (unsigned)hi;
    *(uint2*)(embp + ((size_t)(j2 * 8 + kk) * 64 + l) * 8) = p;
}

// ---- main: fused dist-GEMM (fp8) + double-exp + row softmax ----
// block = 1024 threads (16 waves); tile = 32 rows x 1024 cols;
// wave w owns cols [w*64, w*64+64) x all 32 rows (acc[2][4]).
// A staged in LDS as fp8 fragment-linear planes af[rg*8+kk][slot][8B].
__global__ __launch_bounds__(1024, 8) void sq_main_kernel(
    const float* __restrict__ z, const unsigned char* __restrict__ embp,
    const float* __restrict__ en10, float* __restrict__ out)
{
    __shared__ alignas(16) unsigned char af[16][65][8];  // 8.3 KB
    __shared__ float zn10_s[BM];
    __shared__ float red[BM][16];
    __shared__ float rowinv[BM];

    const int t  = threadIdx.x;
    const int n0 = blockIdx.x * BM;
    const int w  = t >> 6;     // wave id 0..15 (stages rows w, w+16; owns col block w)
    const int l  = t & 63;     // lane

    // ---- stage z: wave w stages rows rg*16+w; fp32 load, -10*norm, fp8 to LDS ----
#pragma unroll
    for (int rg = 0; rg < 2; ++rg) {
        const int r = rg * 16 + w;
        f32x4 v = *(const f32x4*)(z + (size_t)(n0 + r) * DD + l * 4);
        float ss = v.x * v.x + v.y * v.y + v.z * v.z + v.w * v.w;
#pragma unroll
        for (int off = 32; off; off >>= 1) ss += __shfl_xor(ss, off, 64);
        if (l == 0) zn10_s[r] = -10.f * ss;
        int pk = 0;
        pk = __builtin_amdgcn_cvt_pk_fp8_f32(v.x, v.y, pk, false);
        pk = __builtin_amdgcn_cvt_pk_fp8_f32(v.z, v.w, pk, true);
        // cols 4l..4l+3 -> plane kk=l>>3, slot ((l>>1)&3)*16 + w, word (l&1)
        *(unsigned*)&af[rg * 8 + (l >> 3)][((l >> 1) & 3) * 16 + w][(l & 1) * 4] =
            (unsigned)pk;
    }
    __syncthreads();

    const int lr = l & 15, lg = l >> 4;   // B-col (C col) / k-group

    // ---- GEMM: acc[rg][j]; fp8 16x16x32; A re-read per kk (lane-linear) ----
    f32x4 acc[2][4];
#pragma unroll
    for (int rg = 0; rg < 2; ++rg)
#pragma unroll
        for (int j = 0; j < 4; ++j) acc[rg][j] = (f32x4){0.f, 0.f, 0.f, 0.f};

    const unsigned char* bbase = embp + ((size_t)(w * 4) * 8 * 64 + l) * 8;
#pragma unroll
    for (int kk = 0; kk < 8; ++kk) {
        long a0 = *(const long*)&af[kk][l][0];
        long a1 = *(const long*)&af[8 + kk][l][0];
#pragma unroll
        for (int j = 0; j < 4; ++j) {
            long b = *(const long*)(bbase + (size_t)(j * 8 + kk) * 512);
            acc[0][j] = __builtin_amdgcn_mfma_f32_16x16x32_fp8_fp8(a0, b, acc[0][j], 0, 0, 0);
            acc[1][j] = __builtin_amdgcn_mfma_f32_16x16x32_fp8_fp8(a1, b, acc[1][j], 0, 0, 0);
        }
    }

    // ---- epilogue: acc = -1024*(z.e); tt = -10*d = zr10+ec10 - (10/512)*acc ----
    // u = 10*exp(tt) in (0,10]; e = exp(u); no max pass needed.
    float zr10[2][4];
#pragma unroll
    for (int rg = 0; rg < 2; ++rg)
#pragma unroll
        for (int r = 0; r < 4; ++r) zr10[rg][r] = zn10_s[rg * 16 + lg * 4 + r];

    float sum[2][4] = {{0.f, 0.f, 0.f, 0.f}, {0.f, 0.f, 0.f, 0.f}};
#pragma unroll
    for (int j = 0; j < 4; ++j) {
        const float ec10 = en10[w * 64 + j * 16 + lr];
#pragma unroll
        for (int rg = 0; rg < 2; ++rg)
#pragma unroll
            for (int r = 0; r < 4; ++r) {
                const float tt = fmaf(-0.01953125f, acc[rg][j][r], zr10[rg][r] + ec10);
                const float u  = 10.0f * __expf(tt);
                const float e  = __expf(u);
                acc[rg][j][r] = e;
                sum[rg][r] += e;
            }
    }
    // sum across the 16 lanes sharing lg (butterfly within 16-lane groups)
#pragma unroll
    for (int off = 1; off < 16; off <<= 1)
#pragma unroll
        for (int rg = 0; rg < 2; ++rg)
#pragma unroll
            for (int r = 0; r < 4; ++r) sum[rg][r] += __shfl_xor(sum[rg][r], off, 64);
    if (lr == 0)
#pragma unroll
        for (int rg = 0; rg < 2; ++rg)
#pragma unroll
            for (int r = 0; r < 4; ++r) red[rg * 16 + lg * 4 + r][w] = sum[rg][r];
    __syncthreads();

    // ---- stage-2 reduce: 32 threads -> rowinv[32], then broadcast ----
    if (t < BM) {
        const float* p = red[t];
        float s = 0.f;
#pragma unroll
        for (int q = 0; q < 16; ++q) s += p[q];
        rowinv[t] = 1.0f / s;
    }
    __syncthreads();

    float inv[2][4];
#pragma unroll
    for (int rg = 0; rg < 2; ++rg)
#pragma unroll
        for (int r = 0; r < 4; ++r) inv[rg][r] = rowinv[rg * 16 + lg * 4 + r];

    // ---- store: per (j,rg,r) a wave writes 4 x 64B contiguous segments ----
#pragma unroll
    for (int j = 0; j < 4; ++j) {
        const int col = w * 64 + j * 16 + lr;
#pragma unroll
        for (int rg = 0; rg < 2; ++rg)
#pragma unroll
            for (int r = 0; r < 4; ++r) {
                const int row = rg * 16 + lg * 4 + r;
                out[(size_t)(n0 + row) * NE + col] = acc[rg][j][r] * inv[rg][r];
            }
    }
}

extern "C" void kernel_launch(void* const* d_in, const int* in_sizes, int n_in,
                              void* d_out, int out_size, void* d_ws, size_t ws_size,
                              hipStream_t stream) {
    (void)in_sizes; (void)n_in; (void)out_size; (void)ws_size;
    const float* z   = (const float*)d_in[0];
    const float* emb = (const float*)d_in[1];
    float* out = (float*)d_out;
    unsigned char* embp = (unsigned char*)d_ws;
    float* en10 = (float*)((char*)d_ws + (size_t)NE * DD);  // 256KB fp8 pack

    hipLaunchKernelGGL(prep_norm_kernel, dim3(NE / 4), dim3(256), 0, stream,
                       emb, en10);
    hipLaunchKernelGGL(prep_pack_kernel, dim3(64), dim3(512), 0, stream,
                       emb, embp);
    hipLaunchKernelGGL(sq_main_kernel, dim3(NTOK / BM), dim3(1024), 0, stream,
                       z, embp, en10, out);
}

// Round 7
// 51.266 us; speedup vs baseline: 1.4523x; 1.3680x over previous
//
#include <hip/hip_runtime.h>
#include <hip/hip_bf16.h>

#define NTOK 32768
#define NE   1024
#define DD   256
#define BM   32

typedef __attribute__((ext_vector_type(4))) float  f32x4;

// ws layout: embp fp8 pack [256 KB] | en10 [4 KB] | emax2 bits [4 B]

// ---- prep1: en10[row] = -10*||emb_row||^2 ; emax2 = max ||e||^2 (uint bits) ----
__global__ __launch_bounds__(256) void prep_norm_kernel(
    const float* __restrict__ emb, float* __restrict__ en10,
    unsigned int* __restrict__ emax2_bits)
{
    const int t = threadIdx.x;
    const int row = blockIdx.x * 4 + (t >> 6);   // one wave per row
    const int q = t & 63;
    f32x4 v = *(const f32x4*)(emb + (size_t)row * DD + q * 4);
    float ss = v.x * v.x + v.y * v.y + v.z * v.z + v.w * v.w;
#pragma unroll
    for (int off = 32; off; off >>= 1) ss += __shfl_xor(ss, off, 64);
    if (q == 0) {
        en10[row] = -10.f * ss;
        atomicMax(emax2_bits, __float_as_uint(ss));   // ss >= 0: uint cmp == float cmp
    }
}

// ---- prep2: pack fp8(-1024*emb) in MFMA B-fragment-linear order ----
__global__ __launch_bounds__(512) void prep_pack_kernel(
    const float* __restrict__ emb, unsigned char* __restrict__ embp)
{
    const int j2 = blockIdx.x;        // 0..63
    const int kk = threadIdx.x >> 6;  // 0..7
    const int l  = threadIdx.x & 63;
    const int lr = l & 15, lg = l >> 4;
    const float* src = emb + (size_t)(j2 * 16 + lr) * DD + kk * 32 + lg * 8;
    f32x4 a = *(const f32x4*)src;
    f32x4 b = *(const f32x4*)(src + 4);
    const float s = -1024.0f;
    int lo = 0, hi = 0;
    lo = __builtin_amdgcn_cvt_pk_fp8_f32(s * a.x, s * a.y, lo, false);
    lo = __builtin_amdgcn_cvt_pk_fp8_f32(s * a.z, s * a.w, lo, true);
    hi = __builtin_amdgcn_cvt_pk_fp8_f32(s * b.x, s * b.y, hi, false);
    hi = __builtin_amdgcn_cvt_pk_fp8_f32(s * b.z, s * b.w, hi, true);
    uint2 p; p.x = (unsigned)lo; p.y = (unsigned)hi;
    *(uint2*)(embp + ((size_t)(j2 * 8 + kk) * 64 + l) * 8) = p;
}

// ---- main: saturation fast path OR full fused dist-GEMM + softmax ----
// If (||z_n|| - max||e||)^2 >= ~9 for all 32 rows of the tile, every
// softmax input u = 10*exp(-10*d) < 2^-53, so exp(u) == 1.0 exactly in
// fp32 AND fp64 -> row is bit-exactly uniform 1/1024. Else: full R6 path.
__global__ __launch_bounds__(1024, 8) void sq_main_kernel(
    const float* __restrict__ z, const unsigned char* __restrict__ embp,
    const float* __restrict__ en10, const unsigned int* __restrict__ emax2_bits,
    float* __restrict__ out)
{
    __shared__ alignas(16) unsigned char af[16][65][8];  // 8.3 KB (slow path)
    __shared__ float zn10_s[BM];
    __shared__ float red[BM][16];
    __shared__ float rowinv[BM];
    __shared__ int nslow;

    const int t  = threadIdx.x;
    const int n0 = blockIdx.x * BM;
    const int w  = t >> 6;     // wave id 0..15
    const int l  = t & 63;     // lane

    if (t == 0) nslow = 0;
    __syncthreads();

    // saturation threshold: ||z||^2 >= (3 + max||e||)^2  =>  d >= ~8.8
    const float E = sqrtf(__uint_as_float(*emax2_bits));
    const float rhs = (3.0f + E) * (3.0f + E);

    // ---- row norms (z stays in registers for the slow path) ----
    f32x4 v0, v1;
    {
        v0 = *(const f32x4*)(z + (size_t)(n0 + w) * DD + l * 4);
        float ss = v0.x * v0.x + v0.y * v0.y + v0.z * v0.z + v0.w * v0.w;
#pragma unroll
        for (int off = 32; off; off >>= 1) ss += __shfl_xor(ss, off, 64);
        if (l == 0) {
            zn10_s[w] = -10.f * ss;
            if (ss < rhs) atomicAdd(&nslow, 1);
        }
    }
    {
        v1 = *(const f32x4*)(z + (size_t)(n0 + 16 + w) * DD + l * 4);
        float ss = v1.x * v1.x + v1.y * v1.y + v1.z * v1.z + v1.w * v1.w;
#pragma unroll
        for (int off = 32; off; off >>= 1) ss += __shfl_xor(ss, off, 64);
        if (l == 0) {
            zn10_s[16 + w] = -10.f * ss;
            if (ss < rhs) atomicAdd(&nslow, 1);
        }
    }
    __syncthreads();

    if (nslow == 0) {
        // ---- fast path: provably uniform softmax rows ----
        const float c = 0.0009765625f;   // 1/1024
        const f32x4 cv = {c, c, c, c};
        float* ob = out + (size_t)n0 * NE;
#pragma unroll
        for (int i = 0; i < 8; ++i)
            *(f32x4*)(ob + ((size_t)i * 1024 + t) * 4) = cv;
        return;
    }

    // ================= slow path: full R6 computation =================
    // stage z as fp8 fragment-linear planes
    {
        int pk = 0;
        pk = __builtin_amdgcn_cvt_pk_fp8_f32(v0.x, v0.y, pk, false);
        pk = __builtin_amdgcn_cvt_pk_fp8_f32(v0.z, v0.w, pk, true);
        *(unsigned*)&af[(l >> 3)][((l >> 1) & 3) * 16 + w][(l & 1) * 4] = (unsigned)pk;
        pk = 0;
        pk = __builtin_amdgcn_cvt_pk_fp8_f32(v1.x, v1.y, pk, false);
        pk = __builtin_amdgcn_cvt_pk_fp8_f32(v1.z, v1.w, pk, true);
        *(unsigned*)&af[8 + (l >> 3)][((l >> 1) & 3) * 16 + w][(l & 1) * 4] = (unsigned)pk;
    }
    __syncthreads();

    const int lr = l & 15, lg = l >> 4;

    f32x4 acc[2][4];
#pragma unroll
    for (int rg = 0; rg < 2; ++rg)
#pragma unroll
        for (int j = 0; j < 4; ++j) acc[rg][j] = (f32x4){0.f, 0.f, 0.f, 0.f};

    const unsigned char* bbase = embp + ((size_t)(w * 4) * 8 * 64 + l) * 8;
#pragma unroll
    for (int kk = 0; kk < 8; ++kk) {
        long a0 = *(const long*)&af[kk][l][0];
        long a1 = *(const long*)&af[8 + kk][l][0];
#pragma unroll
        for (int j = 0; j < 4; ++j) {
            long b = *(const long*)(bbase + (size_t)(j * 8 + kk) * 512);
            acc[0][j] = __builtin_amdgcn_mfma_f32_16x16x32_fp8_fp8(a0, b, acc[0][j], 0, 0, 0);
            acc[1][j] = __builtin_amdgcn_mfma_f32_16x16x32_fp8_fp8(a1, b, acc[1][j], 0, 0, 0);
        }
    }

    float zr10[2][4];
#pragma unroll
    for (int rg = 0; rg < 2; ++rg)
#pragma unroll
        for (int r = 0; r < 4; ++r) zr10[rg][r] = zn10_s[rg * 16 + lg * 4 + r];

    float sum[2][4] = {{0.f, 0.f, 0.f, 0.f}, {0.f, 0.f, 0.f, 0.f}};
#pragma unroll
    for (int j = 0; j < 4; ++j) {
        const float ec10 = en10[w * 64 + j * 16 + lr];
#pragma unroll
        for (int rg = 0; rg < 2; ++rg)
#pragma unroll
            for (int r = 0; r < 4; ++r) {
                const float tt = fmaf(-0.01953125f, acc[rg][j][r], zr10[rg][r] + ec10);
                const float u  = 10.0f * __expf(tt);
                const float e  = __expf(u);
                acc[rg][j][r] = e;
                sum[rg][r] += e;
            }
    }
#pragma unroll
    for (int off = 1; off < 16; off <<= 1)
#pragma unroll
        for (int rg = 0; rg < 2; ++rg)
#pragma unroll
            for (int r = 0; r < 4; ++r) sum[rg][r] += __shfl_xor(sum[rg][r], off, 64);
    if (lr == 0)
#pragma unroll
        for (int rg = 0; rg < 2; ++rg)
#pragma unroll
            for (int r = 0; r < 4; ++r) red[rg * 16 + lg * 4 + r][w] = sum[rg][r];
    __syncthreads();

    if (t < BM) {
        const float* p = red[t];
        float s = 0.f;
#pragma unroll
        for (int q = 0; q < 16; ++q) s += p[q];
        rowinv[t] = 1.0f / s;
    }
    __syncthreads();

    float inv[2][4];
#pragma unroll
    for (int rg = 0; rg < 2; ++rg)
#pragma unroll
        for (int r = 0; r < 4; ++r) inv[rg][r] = rowinv[rg * 16 + lg * 4 + r];

#pragma unroll
    for (int j = 0; j < 4; ++j) {
        const int col = w * 64 + j * 16 + lr;
#pragma unroll
        for (int rg = 0; rg < 2; ++rg)
#pragma unroll
            for (int r = 0; r < 4; ++r) {
                const int row = rg * 16 + lg * 4 + r;
                out[(size_t)(n0 + row) * NE + col] = acc[rg][j][r] * inv[rg][r];
            }
    }
}

extern "C" void kernel_launch(void* const* d_in, const int* in_sizes, int n_in,
                              void* d_out, int out_size, void* d_ws, size_t ws_size,
                              hipStream_t stream) {
    (void)in_sizes; (void)n_in; (void)out_size; (void)ws_size;
    const float* z   = (const float*)d_in[0];
    const float* emb = (const float*)d_in[1];
    float* out = (float*)d_out;
    unsigned char* embp = (unsigned char*)d_ws;                       // 256 KB
    float* en10 = (float*)((char*)d_ws + (size_t)NE * DD);            // 4 KB
    unsigned int* emax2 = (unsigned int*)((char*)d_ws + (size_t)NE * DD
                                          + NE * sizeof(float));      // 4 B

    hipMemsetAsync(emax2, 0, sizeof(unsigned int), stream);
    hipLaunchKernelGGL(prep_norm_kernel, dim3(NE / 4), dim3(256), 0, stream,
                       emb, en10, emax2);
    hipLaunchKernelGGL(prep_pack_kernel, dim3(64), dim3(512), 0, stream,
                       emb, embp);
    hipLaunchKernelGGL(sq_main_kernel, dim3(NTOK / BM), dim3(1024), 0, stream,
                       z, embp, en10, emax2, out);
}